// Round 10
// baseline (547.437 us; speedup 1.0000x reference)
//
#include <hip/hip_runtime.h>
#include <math.h>

// ---- problem constants ----
#define B_  8
#define S_  577
#define D_  768
#define H_  12
#define P_  576
#define KW_ 32
#define HD_ 64
constexpr int   MS       = B_ * S_;   // 4616
constexpr int   MP       = B_ * P_;   // 4608
constexpr float SCALE_   = 0.125f;
constexpr float INV_TEMP = 10.0f;

typedef __attribute__((ext_vector_type(8))) short bf16x8;
typedef __attribute__((ext_vector_type(4))) float f32x4;

__device__ __forceinline__ unsigned short f2bf(float f) {
  unsigned int x = __float_as_uint(f);
  x += 0x7fffu + ((x >> 16) & 1u);  // RNE
  return (unsigned short)(x >> 16);
}
__device__ __forceinline__ float bf2f(unsigned short h) {
  return __uint_as_float((unsigned int)h << 16);
}
__device__ __forceinline__ void gl_lds16(const unsigned short* g,
                                         unsigned short* l) {
  __builtin_amdgcn_global_load_lds(
      (const __attribute__((address_space(1))) void*)g,
      (__attribute__((address_space(3))) void*)l, 16, 0, 0);
}
__device__ __forceinline__ void unpack8(bf16x8 v, float* f) {
  union { bf16x8 v8; unsigned int w[4]; } u;
  u.v8 = v;
#pragma unroll
  for (int i = 0; i < 4; ++i) {
    f[2 * i]     = __uint_as_float(u.w[i] << 16);
    f[2 * i + 1] = __uint_as_float(u.w[i] & 0xffff0000u);
  }
}
// bijective XCD-chunk swizzle (m204): contiguous wgid chunk per XCD
__device__ __forceinline__ int xcd_swz(int orig, int nwg) {
  const int q = nwg >> 3, r = nwg & 7;
  const int xcd = orig & 7, idx = orig >> 3;
  const int start = (xcd < r) ? xcd * (q + 1) : r * (q + 1) + (xcd - r) * q;
  return start + idx;
}

// ============================================================
// LayerNorm -> bf16 hi (+ optional lo). One block per row.
// ============================================================
template <bool LO>
__global__ __launch_bounds__(256) void ln_rows_bf(
    const float* __restrict__ X, const float* __restrict__ g,
    const float* __restrict__ bta, unsigned short* __restrict__ Yh,
    unsigned short* __restrict__ Yl) {
  const int r = blockIdx.x, tid = threadIdx.x;
  const float* row = X + (long)r * D_;
  float v[3];
  float s = 0.f, sq = 0.f;
#pragma unroll
  for (int t = 0; t < 3; ++t) {
    v[t] = row[tid + t * 256];
    s += v[t];
    sq = fmaf(v[t], v[t], sq);
  }
#pragma unroll
  for (int off = 32; off; off >>= 1) {
    s  += __shfl_xor(s, off);
    sq += __shfl_xor(sq, off);
  }
  __shared__ float rs[4], rq[4];
  if ((tid & 63) == 0) { rs[tid >> 6] = s; rq[tid >> 6] = sq; }
  __syncthreads();
  s  = rs[0] + rs[1] + rs[2] + rs[3];
  sq = rq[0] + rq[1] + rq[2] + rq[3];
  const float m   = s * (1.f / D_);
  const float var = sq * (1.f / D_) - m * m;
  const float inv = rsqrtf(var + 1e-5f);
#pragma unroll
  for (int t = 0; t < 3; ++t) {
    const int c = tid + t * 256;
    const float y = (v[t] - m) * inv * g[c] + bta[c];
    const unsigned short h = f2bf(y);
    Yh[(long)r * D_ + c] = h;
    if (LO) Yl[(long)r * D_ + c] = f2bf(y - bf2f(h));
  }
}

// ============================================================
// l2-normalize fp32 row -> bf16 hi/lo
// ============================================================
__global__ __launch_bounds__(256) void l2norm_hl(
    const float* __restrict__ X, unsigned short* __restrict__ Yh,
    unsigned short* __restrict__ Yl) {
  const int r = blockIdx.x, tid = threadIdx.x;
  const float* row = X + (long)r * D_;
  float v[3];
  float sq = 0.f;
#pragma unroll
  for (int t = 0; t < 3; ++t) {
    v[t] = row[tid + t * 256];
    sq = fmaf(v[t], v[t], sq);
  }
#pragma unroll
  for (int off = 32; off; off >>= 1) sq += __shfl_xor(sq, off);
  __shared__ float rq[4];
  if ((tid & 63) == 0) rq[tid >> 6] = sq;
  __syncthreads();
  sq = rq[0] + rq[1] + rq[2] + rq[3];
  const float sc = 1.f / fmaxf(sqrtf(sq), 1e-12f);
#pragma unroll
  for (int t = 0; t < 3; ++t) {
    const float y = v[t] * sc;
    const unsigned short h = f2bf(y);
    Yh[(long)r * D_ + tid + t * 256] = h;
    Yl[(long)r * D_ + tid + t * 256] = f2bf(y - bf2f(h));
  }
}

// ============================================================
// weight transpose fp32[K][N] -> bf16 [rowoff+N][K] hi (+lo)
// ============================================================
__global__ __launch_bounds__(256) void transpose_hl(
    const float* __restrict__ W, unsigned short* __restrict__ Th,
    unsigned short* __restrict__ Tl, int K, int N, int rowoff) {
  __shared__ float t[32][33];
  const int tx = threadIdx.x & 31, ty = threadIdx.x >> 5;
  const int n0 = blockIdx.x * 32, k0 = blockIdx.y * 32;
#pragma unroll
  for (int i = ty; i < 32; i += 8)
    t[i][tx] = W[(long)(k0 + i) * N + n0 + tx];
  __syncthreads();
#pragma unroll
  for (int i = ty; i < 32; i += 8) {
    const float w = t[tx][i];
    const unsigned short h = f2bf(w);
    const long o = (long)(rowoff + n0 + i) * K + k0 + tx;
    Th[o] = h;
    if (Tl) Tl[o] = f2bf(w - bf2f(h));
  }
}

// ============================================================
// bf16 MFMA GEMM: 128xBN tile, BK=32 double-buffered prefetch.
// slot swizzle: s = p ^ ((row>>1)&3)  (2-way bank alias = free)
// ============================================================
enum { BEPI_QKV = 0, BEPI_ADD = 1, BEPI_GELU = 2 };

template <int EPI, int BN>
__global__ __launch_bounds__(256, 3) void gemm_bf16(
    const unsigned short* __restrict__ A, const unsigned short* __restrict__ Wt,
    const float* __restrict__ bias, const float* __restrict__ R,
    float* __restrict__ C, unsigned short* __restrict__ Cbf,
    int M, int N, int K,
    unsigned short* __restrict__ Qb, unsigned short* __restrict__ Kb,
    unsigned short* __restrict__ Vb) {
  constexpr int BK  = 32;
  constexpr int NJ  = BN / 32;  // j-frags per wave
  constexpr int BCH = BN / 64;  // B staging chunks per thread
  __shared__ __align__(16) unsigned short ldsA[2][128 * BK];
  __shared__ __align__(16) unsigned short ldsB[2][BN * BK];
  const int tid = threadIdx.x, wave = tid >> 6, lane = tid & 63;
  const int wr = wave >> 1, wc = wave & 1;
  const int l16 = lane & 15, l4 = lane >> 4;
  const int NB = N / BN;
  const int wgid = xcd_swz(blockIdx.x, gridDim.x);
  const int bm = wgid / NB, bn = wgid - bm * NB;
  const int row0 = bm * 128;

  f32x4 acc[4][NJ];
#pragma unroll
  for (int i = 0; i < 4; ++i)
#pragma unroll
    for (int j = 0; j < NJ; ++j) acc[i][j] = (f32x4){0.f, 0.f, 0.f, 0.f};

  // staging: chunk c -> LDS 16B slot c; source slot s = p ^ ((r>>1)&3)
  const unsigned short* ga[2];
#pragma unroll
  for (int t = 0; t < 2; ++t) {
    const int c = tid + (t << 8);
    const int r = c >> 2, p = c & 3, s = p ^ ((r >> 1) & 3);
    int ar = row0 + r; if (ar > M - 1) ar = M - 1;
    ga[t] = A + (long)ar * K + (s << 3);
  }
  const unsigned short* gb[BCH];
#pragma unroll
  for (int t = 0; t < BCH; ++t) {
    const int c = tid + (t << 8);
    const int r = c >> 2, p = c & 3, s = p ^ ((r >> 1) & 3);
    gb[t] = Wt + (long)(bn * BN + r) * K + (s << 3);
  }

  const int nt = K / BK;
  // prologue: stage K-step 0 into buffer 0
#pragma unroll
  for (int t = 0; t < 2; ++t)
    gl_lds16(ga[t], &ldsA[0][(tid + (t << 8)) << 3]);
#pragma unroll
  for (int t = 0; t < BCH; ++t)
    gl_lds16(gb[t], &ldsB[0][(tid + (t << 8)) << 3]);
  __syncthreads();

  int cur = 0;
  for (int kt = 0; kt < nt; ++kt) {
    if (kt + 1 < nt) {  // prefetch next K-step into other buffer
      const int k1 = (kt + 1) * BK;
#pragma unroll
      for (int t = 0; t < 2; ++t)
        gl_lds16(ga[t] + k1, &ldsA[cur ^ 1][(tid + (t << 8)) << 3]);
#pragma unroll
      for (int t = 0; t < BCH; ++t)
        gl_lds16(gb[t] + k1, &ldsB[cur ^ 1][(tid + (t << 8)) << 3]);
    }
    bf16x8 af[4], bfr[NJ];
#pragma unroll
    for (int i = 0; i < 4; ++i) {
      const int row = wr * 64 + i * 16 + l16;
      af[i] = *(const bf16x8*)(&ldsA[cur][row * BK +
                                          ((l4 ^ ((row >> 1) & 3)) << 3)]);
    }
#pragma unroll
    for (int j = 0; j < NJ; ++j) {
      const int row = wc * (BN / 2) + j * 16 + l16;
      bfr[j] = *(const bf16x8*)(&ldsB[cur][row * BK +
                                           ((l4 ^ ((row >> 1) & 3)) << 3)]);
    }
#pragma unroll
    for (int i = 0; i < 4; ++i)
#pragma unroll
      for (int j = 0; j < NJ; ++j)
        acc[i][j] = __builtin_amdgcn_mfma_f32_16x16x32_bf16(af[i], bfr[j],
                                                            acc[i][j], 0, 0, 0);
    __syncthreads();  // drains prefetch (issued before compute) + lds reads
    cur ^= 1;
  }

#pragma unroll
  for (int j = 0; j < NJ; ++j) {
    const int gcol = bn * BN + wc * (BN / 2) + j * 16 + l16;
    const float bb = bias[gcol];
#pragma unroll
    for (int i = 0; i < 4; ++i) {
      const int grow0 = row0 + wr * 64 + i * 16 + l4 * 4;
#pragma unroll
      for (int r = 0; r < 4; ++r) {
        const int grow = grow0 + r;
        if (grow >= M) continue;
        float v = acc[i][j][r] + bb;
        if (EPI == BEPI_GELU) {
          v = 0.5f * v * (1.f + erff(v * 0.70710678118654752f));
          Cbf[(long)grow * N + gcol] = f2bf(v);
        } else if (EPI == BEPI_ADD) {
          C[(long)grow * N + gcol] = v + R[(long)grow * N + gcol];
        } else {  // BEPI_QKV: scatter bf16 to (B,H,S,HD)
          const int t   = gcol / (H_ * HD_);
          const int rem = gcol - t * (H_ * HD_);
          const int h   = rem >> 6;
          const int d   = rem & 63;
          const int b   = grow / S_;
          const int ss  = grow - b * S_;
          unsigned short* dst = (t == 0 ? Qb : (t == 1 ? Kb : Vb));
          dst[(((long)(b * H_ + h) * S_ + ss) << 6) + d] = f2bf(v);
        }
      }
    }
  }
}

// ============================================================
// routing projection: bf16x3 emulated-fp32, dbuf prefetch
// ============================================================
__global__ __launch_bounds__(256, 2) void gemm_rproj(
    const unsigned short* __restrict__ Ahi, const unsigned short* __restrict__ Alo,
    const unsigned short* __restrict__ Whi, const unsigned short* __restrict__ Wlo,
    const float* __restrict__ bq, const float* __restrict__ bk,
    float* __restrict__ qout, float* __restrict__ kout) {
  constexpr int BK = 32, K = D_, NB = 12;
  __shared__ __align__(16) unsigned short ldsAh[2][128 * BK];
  __shared__ __align__(16) unsigned short ldsAl[2][128 * BK];
  __shared__ __align__(16) unsigned short ldsBh[2][128 * BK];
  __shared__ __align__(16) unsigned short ldsBl[2][128 * BK];
  const int tid = threadIdx.x, wave = tid >> 6, lane = tid & 63;
  const int wr = wave >> 1, wc = wave & 1;
  const int l16 = lane & 15, l4 = lane >> 4;
  const int wgid = xcd_swz(blockIdx.x, gridDim.x);
  const int bm = wgid / NB, bn = wgid - bm * NB;
  const int row0 = bm * 128;

  f32x4 acc[4][4];
#pragma unroll
  for (int i = 0; i < 4; ++i)
#pragma unroll
    for (int j = 0; j < 4; ++j) acc[i][j] = (f32x4){0.f, 0.f, 0.f, 0.f};

  long aoff[2], boff[2];
#pragma unroll
  for (int t = 0; t < 2; ++t) {
    const int c = tid + (t << 8);
    const int r = c >> 2, p = c & 3, s = p ^ ((r >> 1) & 3);
    const int rg = row0 + r;
    aoff[t] = (long)(rg + rg / P_ + 1) * K + (s << 3);
    boff[t] = (long)(bn * 128 + r) * K + (s << 3);
  }

  const int nt = K / BK;
#pragma unroll
  for (int t = 0; t < 2; ++t) {
    const int lo = (tid + (t << 8)) << 3;
    gl_lds16(Ahi + aoff[t], &ldsAh[0][lo]);
    gl_lds16(Alo + aoff[t], &ldsAl[0][lo]);
    gl_lds16(Whi + boff[t], &ldsBh[0][lo]);
    gl_lds16(Wlo + boff[t], &ldsBl[0][lo]);
  }
  __syncthreads();

  int cur = 0;
  for (int kt = 0; kt < nt; ++kt) {
    if (kt + 1 < nt) {
      const int k1 = (kt + 1) * BK;
#pragma unroll
      for (int t = 0; t < 2; ++t) {
        const int lo = (tid + (t << 8)) << 3;
        gl_lds16(Ahi + aoff[t] + k1, &ldsAh[cur ^ 1][lo]);
        gl_lds16(Alo + aoff[t] + k1, &ldsAl[cur ^ 1][lo]);
        gl_lds16(Whi + boff[t] + k1, &ldsBh[cur ^ 1][lo]);
        gl_lds16(Wlo + boff[t] + k1, &ldsBl[cur ^ 1][lo]);
      }
    }
    bf16x8 ah[4], al[4], bh[4], bl[4];
#pragma unroll
    for (int i = 0; i < 4; ++i) {
      const int row = wr * 64 + i * 16 + l16;
      const int off = row * BK + ((l4 ^ ((row >> 1) & 3)) << 3);
      ah[i] = *(const bf16x8*)(&ldsAh[cur][off]);
      al[i] = *(const bf16x8*)(&ldsAl[cur][off]);
    }
#pragma unroll
    for (int j = 0; j < 4; ++j) {
      const int row = wc * 64 + j * 16 + l16;
      const int off = row * BK + ((l4 ^ ((row >> 1) & 3)) << 3);
      bh[j] = *(const bf16x8*)(&ldsBh[cur][off]);
      bl[j] = *(const bf16x8*)(&ldsBl[cur][off]);
    }
#pragma unroll
    for (int i = 0; i < 4; ++i)
#pragma unroll
      for (int j = 0; j < 4; ++j) {
        acc[i][j] = __builtin_amdgcn_mfma_f32_16x16x32_bf16(ah[i], bh[j], acc[i][j], 0, 0, 0);
        acc[i][j] = __builtin_amdgcn_mfma_f32_16x16x32_bf16(ah[i], bl[j], acc[i][j], 0, 0, 0);
        acc[i][j] = __builtin_amdgcn_mfma_f32_16x16x32_bf16(al[i], bh[j], acc[i][j], 0, 0, 0);
      }
    __syncthreads();
    cur ^= 1;
  }

#pragma unroll
  for (int j = 0; j < 4; ++j) {
    const int gcol = bn * 128 + wc * 64 + j * 16 + l16;
    const float bb = (gcol < D_) ? bq[gcol] : bk[gcol - D_];
#pragma unroll
    for (int i = 0; i < 4; ++i) {
      const int grow0 = row0 + wr * 64 + i * 16 + l4 * 4;
#pragma unroll
      for (int r = 0; r < 4; ++r) {
        const int grow = grow0 + r;
        const float v = acc[i][j][r] + bb;
        if (gcol < D_) qout[(long)grow * D_ + gcol] = v;
        else           kout[(long)grow * D_ + gcol - D_] = v;
      }
    }
  }
}

// ============================================================
// routing scores: batched bf16x3 NT, dbuf prefetch
// ============================================================
__global__ __launch_bounds__(256, 2) void gemm_scores(
    const unsigned short* __restrict__ Qh, const unsigned short* __restrict__ Ql,
    const unsigned short* __restrict__ Kh, const unsigned short* __restrict__ Kl,
    const float* __restrict__ pos, float* __restrict__ sc) {
  constexpr int BK = 32, K = D_;
  __shared__ __align__(16) unsigned short ldsAh[2][128 * BK];
  __shared__ __align__(16) unsigned short ldsAl[2][128 * BK];
  __shared__ __align__(16) unsigned short ldsBh[2][128 * BK];
  __shared__ __align__(16) unsigned short ldsBl[2][128 * BK];
  const int tid = threadIdx.x, wave = tid >> 6, lane = tid & 63;
  const int wr = wave >> 1, wc = wave & 1;
  const int l16 = lane & 15, l4 = lane >> 4;
  const int bn = blockIdx.x, bm = blockIdx.y, b = blockIdx.z;
  const long base = (long)b * P_ * K;
  const int row0 = bm * 128;

  f32x4 acc[4][4];
#pragma unroll
  for (int i = 0; i < 4; ++i)
#pragma unroll
    for (int j = 0; j < 4; ++j) acc[i][j] = (f32x4){0.f, 0.f, 0.f, 0.f};

  long aoff[2], boff[2];
#pragma unroll
  for (int t = 0; t < 2; ++t) {
    const int c = tid + (t << 8);
    const int r = c >> 2, p = c & 3, s = p ^ ((r >> 1) & 3);
    int ar = row0 + r;      if (ar > P_ - 1) ar = P_ - 1;
    int br = bn * 128 + r;  if (br > P_ - 1) br = P_ - 1;
    aoff[t] = base + (long)ar * K + (s << 3);
    boff[t] = base + (long)br * K + (s << 3);
  }

  const int nt = K / BK;
#pragma unroll
  for (int t = 0; t < 2; ++t) {
    const int lo = (tid + (t << 8)) << 3;
    gl_lds16(Qh + aoff[t], &ldsAh[0][lo]);
    gl_lds16(Ql + aoff[t], &ldsAl[0][lo]);
    gl_lds16(Kh + boff[t], &ldsBh[0][lo]);
    gl_lds16(Kl + boff[t], &ldsBl[0][lo]);
  }
  __syncthreads();

  int cur = 0;
  for (int kt = 0; kt < nt; ++kt) {
    if (kt + 1 < nt) {
      const int k1 = (kt + 1) * BK;
#pragma unroll
      for (int t = 0; t < 2; ++t) {
        const int lo = (tid + (t << 8)) << 3;
        gl_lds16(Qh + aoff[t] + k1, &ldsAh[cur ^ 1][lo]);
        gl_lds16(Ql + aoff[t] + k1, &ldsAl[cur ^ 1][lo]);
        gl_lds16(Kh + boff[t] + k1, &ldsBh[cur ^ 1][lo]);
        gl_lds16(Kl + boff[t] + k1, &ldsBl[cur ^ 1][lo]);
      }
    }
    bf16x8 ah[4], al[4], bh[4], bl[4];
#pragma unroll
    for (int i = 0; i < 4; ++i) {
      const int row = wr * 64 + i * 16 + l16;
      const int off = row * BK + ((l4 ^ ((row >> 1) & 3)) << 3);
      ah[i] = *(const bf16x8*)(&ldsAh[cur][off]);
      al[i] = *(const bf16x8*)(&ldsAl[cur][off]);
    }
#pragma unroll
    for (int j = 0; j < 4; ++j) {
      const int row = wc * 64 + j * 16 + l16;
      const int off = row * BK + ((l4 ^ ((row >> 1) & 3)) << 3);
      bh[j] = *(const bf16x8*)(&ldsBh[cur][off]);
      bl[j] = *(const bf16x8*)(&ldsBl[cur][off]);
    }
#pragma unroll
    for (int i = 0; i < 4; ++i)
#pragma unroll
      for (int j = 0; j < 4; ++j) {
        acc[i][j] = __builtin_amdgcn_mfma_f32_16x16x32_bf16(ah[i], bh[j], acc[i][j], 0, 0, 0);
        acc[i][j] = __builtin_amdgcn_mfma_f32_16x16x32_bf16(ah[i], bl[j], acc[i][j], 0, 0, 0);
        acc[i][j] = __builtin_amdgcn_mfma_f32_16x16x32_bf16(al[i], bh[j], acc[i][j], 0, 0, 0);
      }
    __syncthreads();
    cur ^= 1;
  }

#pragma unroll
  for (int j = 0; j < 4; ++j) {
    const int gj = bn * 128 + wc * 64 + j * 16 + l16;
    if (gj >= P_) continue;
#pragma unroll
    for (int i = 0; i < 4; ++i) {
      const int grow0 = row0 + wr * 64 + i * 16 + l4 * 4;
#pragma unroll
      for (int r = 0; r < 4; ++r) {
        const int gi = grow0 + r;
        if (gi >= P_) continue;
        const float s = (gi == gj) ? -1e9f : acc[i][j][r] + pos[(long)gi * P_ + gj];
        sc[((long)b * P_ + gi) * P_ + gj] = s * INV_TEMP;
      }
    }
  }
}

// ============================================================
// top-32 + log-softmax weights. One wave per row.
// ============================================================
__global__ __launch_bounds__(64) void topk_route(
    const float* __restrict__ sc, int* __restrict__ routes,
    float* __restrict__ logw) {
  const int row = blockIdx.x, lane = threadIdx.x;
  const float* srow = sc + (long)row * P_;
  float v[9];
#pragma unroll
  for (int t = 0; t < 9; ++t) v[t] = srow[lane + (t << 6)];
  float selv = 0.f;
  int   selj = 0;
  for (int it = 0; it < KW_; ++it) {
    float bv = -3.0e38f;
    int   bj = 0x7fffffff;
#pragma unroll
    for (int t = 0; t < 9; ++t) {
      if (v[t] > bv) { bv = v[t]; bj = lane + (t << 6); }
    }
#pragma unroll
    for (int off = 32; off; off >>= 1) {
      const float ov = __shfl_xor(bv, off);
      const int   oj = __shfl_xor(bj, off);
      if (ov > bv || (ov == bv && oj < bj)) { bv = ov; bj = oj; }
    }
    if (lane == it) { selv = bv; selj = bj; }
    if ((bj & 63) == lane) v[bj >> 6] = -3.0e38f;
  }
  const float x = (lane < KW_) ? selv : -3.0e38f;
  float m = x;
#pragma unroll
  for (int off = 16; off; off >>= 1) m = fmaxf(m, __shfl_xor(m, off));
  const float e = expf(x - m);
  float s = e;
#pragma unroll
  for (int off = 16; off; off >>= 1) s += __shfl_xor(s, off);
  const float lw = fmaxf(x - m - logf(s), -10.0f);
  if (lane < KW_) {
    routes[(long)row * KW_ + lane] = selj;
    logw[(long)row * KW_ + lane]   = lw;
  }
}

// ============================================================
// patch attention v2 (unchanged)
// ============================================================
__global__ __launch_bounds__(1024, 1) void patch_attn2(
    const unsigned short* __restrict__ Qb, const unsigned short* __restrict__ Kb,
    const unsigned short* __restrict__ Vb, const int* __restrict__ routes,
    const float* __restrict__ logw, unsigned short* __restrict__ attn) {
  __shared__ __align__(16) unsigned short ldsK[P_ * HD_];
  __shared__ __align__(16) unsigned short ldsV[P_ * HD_];
  const int tid = threadIdx.x;
  const int b = blockIdx.x & 7;
  const int rest = blockIdx.x >> 3;
  const int phalf = rest & 1;
  const int h = rest >> 1;
  const long hb = ((long)(b * H_ + h) * S_) << 6;

  const unsigned short* kg = Kb + hb + HD_;
  const unsigned short* vg = Vb + hb + HD_;
#pragma unroll
  for (int c = tid; c < P_ * 8; c += 1024) {
    const int r = c >> 3, i = c & 7;
    const int lo = r * 64 + ((i * 8) ^ ((r & 7) << 3));
    *(bf16x8*)(ldsK + lo) = *(const bf16x8*)(kg + c * 8);
    *(bf16x8*)(ldsV + lo) = *(const bf16x8*)(vg + c * 8);
  }
  __syncthreads();

  const int wave = tid >> 6, lane = tid & 63;
  const int g = lane >> 3, ch = lane & 7;
  const int p0 = phalf * 288;

  for (int p = p0 + wave; p < p0 + 288; p += 16) {
    const int s = p + 1;
    const long bp32 = ((long)(b * P_ + p)) << 5;
    float qf[8];
    unpack8(*(const bf16x8*)(Qb + hb + ((long)s << 6) + ch * 8), qf);
    int   rk[4];
    float sc4[4];
    float m = -3.0e38f;
#pragma unroll
    for (int it = 0; it < 4; ++it) {
      const int key = it * 8 + g;
      rk[it] = routes[bp32 + key];
      float kf[8];
      unpack8(*(const bf16x8*)(ldsK + rk[it] * 64 +
                               ((ch * 8) ^ ((rk[it] & 7) << 3))), kf);
      float d0 = 0.f;
#pragma unroll
      for (int d = 0; d < 8; ++d) d0 = fmaf(qf[d], kf[d], d0);
      d0 += __shfl_xor(d0, 1);
      d0 += __shfl_xor(d0, 2);
      d0 += __shfl_xor(d0, 4);
      sc4[it] = fmaf(d0, SCALE_, logw[bp32 + key]);
      m = fmaxf(m, sc4[it]);
    }
    m = fmaxf(m, __shfl_xor(m, 8));
    m = fmaxf(m, __shfl_xor(m, 16));
    m = fmaxf(m, __shfl_xor(m, 32));
    float e4[4], lsum = 0.f;
#pragma unroll
    for (int it = 0; it < 4; ++it) {
      e4[it] = __expf(sc4[it] - m);
      lsum += e4[it];
    }
    lsum += __shfl_xor(lsum, 8);
    lsum += __shfl_xor(lsum, 16);
    lsum += __shfl_xor(lsum, 32);
    float facc[8];
#pragma unroll
    for (int d = 0; d < 8; ++d) facc[d] = 0.f;
#pragma unroll
    for (int it = 0; it < 4; ++it) {
      float vf[8];
      unpack8(*(const bf16x8*)(ldsV + rk[it] * 64 +
                               ((ch * 8) ^ ((rk[it] & 7) << 3))), vf);
#pragma unroll
      for (int d = 0; d < 8; ++d) facc[d] = fmaf(e4[it], vf[d], facc[d]);
    }
#pragma unroll
    for (int off = 8; off <= 32; off <<= 1)
#pragma unroll
      for (int d = 0; d < 8; ++d) facc[d] += __shfl_xor(facc[d], off);
    const float inv = 1.f / lsum;
    if (lane < 8) {
      union { bf16x8 v8; unsigned short u[8]; } o;
#pragma unroll
      for (int d = 0; d < 8; ++d) o.u[d] = f2bf(facc[d] * inv);
      *(bf16x8*)(attn + ((long)b * S_ + s) * D_ + h * HD_ + ch * 8) = o.v8;
    }
  }
}

// ============================================================
// cls-token attention (bf16 in/out)
// ============================================================
__global__ __launch_bounds__(256) void cls_attn(
    const unsigned short* __restrict__ Qb, const unsigned short* __restrict__ Kb,
    const unsigned short* __restrict__ Vb, unsigned short* __restrict__ attn) {
  const int bh = blockIdx.x;
  const int b = bh / H_, h = bh - b * H_;
  const int tid = threadIdx.x;
  __shared__ float qs[HD_];
  __shared__ float ssh[S_];
  __shared__ float redm[4], reds[4];
  __shared__ float osh[4][HD_];
  const unsigned short* Qrow  = Qb + (long)bh * S_ * HD_;
  const unsigned short* Kbase = Kb + (long)bh * S_ * HD_;
  const unsigned short* Vbase = Vb + (long)bh * S_ * HD_;
  if (tid < HD_) qs[tid] = bf2f(Qrow[tid]);
  __syncthreads();
  float lmax = -3.0e38f;
  for (int j = tid; j < S_; j += 256) {
    const unsigned short* kr = Kbase + (long)j * HD_;
    float dot = 0.f;
#pragma unroll
    for (int dd = 0; dd < HD_; dd += 8) {
      float kf[8];
      unpack8(*(const bf16x8*)(kr + dd), kf);
#pragma unroll
      for (int t = 0; t < 8; ++t) dot = fmaf(kf[t], qs[dd + t], dot);
    }
    dot *= SCALE_;
    ssh[j] = dot;
    lmax = fmaxf(lmax, dot);
  }
#pragma unroll
  for (int off = 32; off; off >>= 1) lmax = fmaxf(lmax, __shfl_xor(lmax, off));
  if ((tid & 63) == 0) redm[tid >> 6] = lmax;
  __syncthreads();
  const float m = fmaxf(fmaxf(redm[0], redm[1]), fmaxf(redm[2], redm[3]));
  float lsum = 0.f;
  for (int j = tid; j < S_; j += 256) {
    const float e = expf(ssh[j] - m);
    ssh[j] = e;
    lsum += e;
  }
#pragma unroll
  for (int off = 32; off; off >>= 1) lsum += __shfl_xor(lsum, off);
  if ((tid & 63) == 0) reds[tid >> 6] = lsum;
  __syncthreads();
  const float inv = 1.f / (reds[0] + reds[1] + reds[2] + reds[3]);
  const int d = tid & 63, qt = tid >> 6;
  float acc = 0.f;
  for (int j = qt; j < S_; j += 4)
    acc = fmaf(ssh[j], bf2f(Vbase[((long)j << 6) + d]), acc);
  osh[qt][d] = acc;
  __syncthreads();
  if (tid < HD_) {
    const float o = (osh[0][tid] + osh[1][tid] + osh[2][tid] + osh[3][tid]) * inv;
    attn[(long)b * S_ * D_ + h * HD_ + tid] = f2bf(o);
  }
}

// ============================================================
// host-side launch
// ============================================================
extern "C" void kernel_launch(void* const* d_in, const int* in_sizes, int n_in,
                              void* d_out, int out_size, void* d_ws,
                              size_t ws_size, hipStream_t stream) {
  const float* x     = (const float*)d_in[0];
  const float* g1    = (const float*)d_in[1];
  const float* b1    = (const float*)d_in[2];
  const float* wq    = (const float*)d_in[3];
  const float* bq    = (const float*)d_in[4];
  const float* wk    = (const float*)d_in[5];
  const float* bk    = (const float*)d_in[6];
  const float* pos   = (const float*)d_in[7];
  const float* wqkv  = (const float*)d_in[8];
  const float* bqkv  = (const float*)d_in[9];
  const float* wproj = (const float*)d_in[10];
  const float* bproj = (const float*)d_in[11];
  const float* g2    = (const float*)d_in[12];
  const float* b2    = (const float*)d_in[13];
  const float* wm1   = (const float*)d_in[14];
  const float* bm1   = (const float*)d_in[15];
  const float* wm2   = (const float*)d_in[16];
  const float* bm2   = (const float*)d_in[17];
  float* out = (float*)d_out;

  constexpr long NSD = (long)MS * D_;       // 3,545,088 (== B*H*S*HD)
  constexpr long MPD = (long)MP * D_;       // 3,538,944
  constexpr long SCL = (long)B_ * P_ * P_;  // 2,654,208

  unsigned short* xn_hi = (unsigned short*)d_ws;
  unsigned short* xn_lo = xn_hi + NSD;
  float* x1 = (float*)(xn_lo + NSD);
  unsigned short* Qb = (unsigned short*)(x1 + NSD);
  unsigned short* Kb = Qb + NSD;
  unsigned short* Vb = Kb + NSD;
  int*   routes = (int*)(Vb + NSD);
  float* logw   = (float*)(routes + (long)MP * KW_);
  float* R1   = logw + (long)MP * KW_;
  float* qbuf = R1;
  float* kbuf = qbuf + MPD;
  unsigned short* h_bf = (unsigned short*)R1;        // 4616*3072 shorts
  constexpr long R1LEN = ((long)MS * 3072 + 1) / 2;  // floats
  float* scb = R1 + R1LEN;
  unsigned short* qh = (unsigned short*)(scb + SCL);
  unsigned short* ql = qh + MPD;
  unsigned short* kh = ql + MPD;
  unsigned short* kl = kh + MPD;
  unsigned short* x1n_bf  = qh;        // NSD shorts, live after scores dead
  unsigned short* attn_bf = qh + NSD;  // NSD shorts
  unsigned short* wqk_hi  = kl + MPD;                   // [1536][768]
  unsigned short* wqk_lo  = wqk_hi + (long)1536 * 768;
  unsigned short* wqkv_t  = wqk_lo + (long)1536 * 768;  // [2304][768]
  unsigned short* wproj_t = wqkv_t + (long)2304 * 768;  // [768][768]
  unsigned short* wm1_t   = wproj_t + (long)768 * 768;  // [3072][768]
  unsigned short* wm2_t   = wm1_t + (long)3072 * 768;   // [768][3072]

  // weight prep
  transpose_hl<<<dim3(24, 24), 256, 0, stream>>>(wq, wqk_hi, wqk_lo, 768, 768, 0);
  transpose_hl<<<dim3(24, 24), 256, 0, stream>>>(wk, wqk_hi, wqk_lo, 768, 768, 768);
  transpose_hl<<<dim3(72, 24), 256, 0, stream>>>(wqkv, wqkv_t, nullptr, 768, 2304, 0);
  transpose_hl<<<dim3(24, 24), 256, 0, stream>>>(wproj, wproj_t, nullptr, 768, 768, 0);
  transpose_hl<<<dim3(96, 24), 256, 0, stream>>>(wm1, wm1_t, nullptr, 768, 3072, 0);
  transpose_hl<<<dim3(24, 96), 256, 0, stream>>>(wm2, wm2_t, nullptr, 3072, 768, 0);

  // 1. LN1 -> bf16 hi/lo
  ln_rows_bf<true><<<MS, 256, 0, stream>>>(x, g1, b1, xn_hi, xn_lo);
  // 2. routing projections (bf16x3), q|k fused, dbuf prefetch
  gemm_rproj<<<12 * 36, 256, 0, stream>>>(xn_hi, xn_lo, wqk_hi, wqk_lo, bq, bk,
                                          qbuf, kbuf);
  // 3. l2norm -> hi/lo
  l2norm_hl<<<MP, 256, 0, stream>>>(qbuf, qh, ql);
  l2norm_hl<<<MP, 256, 0, stream>>>(kbuf, kh, kl);
  // 4. routing scores (bf16x3, batched, fused pos/diag/x10)
  gemm_scores<<<dim3(5, 5, B_), 256, 0, stream>>>(qh, ql, kh, kl, pos, scb);
  // 5. top-32 + log-softmax
  topk_route<<<MP, 64, 0, stream>>>(scb, routes, logw);
  // 6. fused QKV projection (bf16 MFMA) -> (B,H,S,HD) bf16
  gemm_bf16<BEPI_QKV, 128><<<18 * 37, 256, 0, stream>>>(
      xn_hi, wqkv_t, bqkv, nullptr, nullptr, nullptr, MS, 2304, D_, Qb, Kb, Vb);
  // 7. attention (bf16 in, fp32 compute, bf16 out)
  cls_attn<<<B_ * H_, 256, 0, stream>>>(Qb, Kb, Vb, attn_bf);
  patch_attn2<<<192, 1024, 0, stream>>>(Qb, Kb, Vb, routes, logw, attn_bf);
  // 8. output projection + residual (BN=64: doubles grid for N=768)
  gemm_bf16<BEPI_ADD, 64><<<12 * 37, 256, 0, stream>>>(
      attn_bf, wproj_t, bproj, x, x1, nullptr, MS, D_, D_, nullptr, nullptr,
      nullptr);
  // 9. LN2 + MLP
  ln_rows_bf<false><<<MS, 256, 0, stream>>>(x1, g2, b2, x1n_bf, nullptr);
  gemm_bf16<BEPI_GELU, 128><<<24 * 37, 256, 0, stream>>>(
      x1n_bf, wm1_t, bm1, nullptr, nullptr, h_bf, MS, 3072, D_, nullptr,
      nullptr, nullptr);
  gemm_bf16<BEPI_ADD, 64><<<12 * 37, 256, 0, stream>>>(
      h_bf, wm2_t, bm2, x1, out, nullptr, MS, D_, 3072, nullptr, nullptr,
      nullptr);
}